// Round 15
// baseline (100.467 us; speedup 1.0000x reference)
//
#include <hip/hip_runtime.h>

constexpr int N_NODES = 100000;
constexpr int D       = 64;
constexpr int N_EDGES = 1600000;
constexpr int OUT_N4  = N_NODES * D / 4;

constexpr int NPB   = 128;                           // nodes per bucket
constexpr int NBUCK = (N_NODES + NPB - 1) / NPB;     // 782
constexpr int BCAP  = 2560;                          // slots/bucket (λ=2046, +11σ)
constexpr int CPAD  = 32;                            // cursor pad (ints) = 128B/line
constexpr int PTHREADS = 1024;                       // part: 16 waves/block
constexpr int EPT   = 4;                             // part: edges per thread
constexpr int CHUNK = PTHREADS * EPT;                // 4096
constexpr int PB    = (N_EDGES + CHUNK - 1) / CHUNK; // 391
constexpr int SGT   = 512;                           // sg: 8 waves/block

constexpr float FXSCALE  = 262144.0f;       // 2^18 fixed-point scale
constexpr float FXINV    = 1.0f / FXSCALE;

// ---------------------------------------------------------------------------
__global__ void detect_kernel(const unsigned long long* __restrict__ ei,
                              int* __restrict__ flag) {
    if (blockIdx.x == 0 && threadIdx.x == 0) {
        int is64 = 1;
#pragma unroll
        for (int i = 0; i < 8; ++i)
            if (ei[i] >= (unsigned long long)N_NODES) is64 = 0;
        *flag = is64;
    }
}

__device__ __forceinline__ int load_idx(const void* ei_raw, int flag, long long pos) {
    if (flag) return (int)((const long long*)ei_raw)[pos];
    return ((const int*)ei_raw)[pos];
}

__device__ __forceinline__ unsigned short bf16rne(float f) {
    unsigned u = __float_as_uint(f);
    unsigned r = (u + 0x7fffu + ((u >> 16) & 1u)) >> 16;
    return (unsigned short)r;
}
__device__ __forceinline__ float bf16f(unsigned short u) {
    return __uint_as_float(((unsigned)u) << 16);
}

// ---------------------------------------------------------------------------
// Partition (+ fused bf16 conversion prologue): register-staged edges,
// in-LDS bucket sort, coalesced write-out.
__global__ __launch_bounds__(PTHREADS) void part_kernel(
        const float4* __restrict__ x4,
        ushort4* __restrict__ x16v,
        const void* __restrict__ ei_raw,
        const float* __restrict__ ew,
        const int* __restrict__ flag,
        int* __restrict__ cursor,
        int2* __restrict__ slots) {
    __shared__ int  hist[NBUCK];
    __shared__ int  localbase[NBUCK];
    __shared__ int  runbase[NBUCK];
    __shared__ int  fill[NBUCK];
    __shared__ int  wsum[16];
    __shared__ int  tot;
    __shared__ int2 srt[CHUNK];           // 32 KB
    __shared__ unsigned short aux[CHUNK]; // 8 KB

    int tid  = threadIdx.x;
    int wv   = tid >> 6;
    int lane = tid & 63;
    for (int t = tid; t < NBUCK; t += PTHREADS) { hist[t] = 0; fill[t] = 0; }
    __syncthreads();

    // fused prologue: bf16 shadow of x
    {
        int gstride = PB * PTHREADS;
        for (int i = blockIdx.x * PTHREADS + tid; i < OUT_N4; i += gstride) {
            float4 v = x4[i];
            ushort4 o;
            o.x = bf16rne(v.x); o.y = bf16rne(v.y);
            o.z = bf16rne(v.z); o.w = bf16rne(v.w);
            x16v[i] = o;
        }
    }

    int f = *flag;
    long long base = (long long)blockIdx.x * CHUNK;

    int  rb[EPT];
    int2 rrec[EPT];
#pragma unroll
    for (int it = 0; it < EPT; ++it) {
        long long e = base + it * PTHREADS + tid;
        if (e < N_EDGES) {
            int src = load_idx(ei_raw, f, e);
            int dst = load_idx(ei_raw, f, (long long)N_EDGES + e);
            int b = dst >> 7;
            rb[it] = b;
            rrec[it].x = (src << 7) | (dst & (NPB - 1));
            rrec[it].y = __float_as_int(ew[e]);
            atomicAdd(&hist[b], 1);
        } else {
            rb[it] = -1;
        }
    }
    __syncthreads();

    // exclusive scan of hist[NBUCK] via shfl wave-scan
    int h = (tid < NBUCK) ? hist[tid] : 0;
    int v = h;
#pragma unroll
    for (int off = 1; off < 64; off <<= 1) {
        int u = __shfl_up(v, off, 64);
        if (lane >= off) v += u;
    }
    if (lane == 63) wsum[wv] = v;
    __syncthreads();
    if (wv == 0 && lane < 16) {
        int s = wsum[lane];
        int t2 = s;
#pragma unroll
        for (int off = 1; off < 16; off <<= 1) {
            int u = __shfl_up(t2, off, 64);
            if (lane >= off) t2 += u;
        }
        wsum[lane] = t2 - s;
        if (lane == 15) tot = t2;
    }
    __syncthreads();
    if (tid < NBUCK) {
        localbase[tid] = (v - h) + wsum[wv];
        int c = hist[tid];
        runbase[tid] = (c > 0) ? atomicAdd(&cursor[tid * CPAD], c) : 0;
    }
    __syncthreads();

#pragma unroll
    for (int it = 0; it < EPT; ++it) {
        int b = rb[it];
        if (b >= 0) {
            int p = localbase[b] + atomicAdd(&fill[b], 1);
            srt[p] = rrec[it];
            aux[p] = (unsigned short)b;
        }
    }
    __syncthreads();

    int total = tot;
    for (int i = tid; i < total; i += PTHREADS) {
        int b = aux[i];
        int g = runbase[b] + (i - localbase[b]);
        if (g < BCAP) slots[(long long)b * BCAP + g] = srt[i];
    }
}

// ---------------------------------------------------------------------------
// Gather v4: sort-free, fixed-point LDS accumulation (int ds_add — native,
// unlike f32 LDS atomicAdd which is a serializing CAS on gfx950: round 13).
// One block (512 thr, 8 waves) per bucket; acc[128][64] int (32 KB).
// Per record: wave-uniform 8B record read (scalar), coalesced random 128B
// bf16 row load (lane=dim), one conflict-free ds_add into the node row
// (stride 4B: 2 lanes/bank = free). Unroll 8 for MLP. Epilogue:
// relu(x + W*acc*2^-18) from LDS.
__global__ __launch_bounds__(SGT) void sg_kernel(
        const unsigned short* __restrict__ x16,
        const int* __restrict__ cursor,
        const int2* __restrict__ slots,
        const float* __restrict__ weight,
        float* __restrict__ out) {
    __shared__ int acc[NPB * 64];   // 32 KB

    int tid  = threadIdx.x;
    int wv   = tid >> 6;
    int lane = tid & 63;
    int b    = blockIdx.x;

    int4* a4 = (int4*)acc;
    int4 z = make_int4(0, 0, 0, 0);
    for (int i = tid; i < NPB * 16; i += SGT) a4[i] = z;

    int cnt = cursor[b * CPAD];
    if (cnt > BCAP) cnt = BCAP;
    const int2* sb = slots + (long long)b * BCAP;
    __syncthreads();

    // contiguous per-wave record range (wave-uniform -> scalar record loads)
    int per = (cnt + 7) >> 3;
    int beg = wv * per;
    int end = beg + per;
    if (end > cnt) end = cnt;

    int k = beg;
    for (; k + 8 <= end; k += 8) {
        int2 r0 = sb[k];     int2 r1 = sb[k + 1];
        int2 r2 = sb[k + 2]; int2 r3 = sb[k + 3];
        int2 r4 = sb[k + 4]; int2 r5 = sb[k + 5];
        int2 r6 = sb[k + 6]; int2 r7 = sb[k + 7];
        float v0 = bf16f(x16[(r0.x >> 7) * D + lane]);
        float v1 = bf16f(x16[(r1.x >> 7) * D + lane]);
        float v2 = bf16f(x16[(r2.x >> 7) * D + lane]);
        float v3 = bf16f(x16[(r3.x >> 7) * D + lane]);
        float v4 = bf16f(x16[(r4.x >> 7) * D + lane]);
        float v5 = bf16f(x16[(r5.x >> 7) * D + lane]);
        float v6 = bf16f(x16[(r6.x >> 7) * D + lane]);
        float v7 = bf16f(x16[(r7.x >> 7) * D + lane]);
        atomicAdd(&acc[(r0.x & (NPB - 1)) * 64 + lane],
                  __float2int_rn(__int_as_float(r0.y) * v0 * FXSCALE));
        atomicAdd(&acc[(r1.x & (NPB - 1)) * 64 + lane],
                  __float2int_rn(__int_as_float(r1.y) * v1 * FXSCALE));
        atomicAdd(&acc[(r2.x & (NPB - 1)) * 64 + lane],
                  __float2int_rn(__int_as_float(r2.y) * v2 * FXSCALE));
        atomicAdd(&acc[(r3.x & (NPB - 1)) * 64 + lane],
                  __float2int_rn(__int_as_float(r3.y) * v3 * FXSCALE));
        atomicAdd(&acc[(r4.x & (NPB - 1)) * 64 + lane],
                  __float2int_rn(__int_as_float(r4.y) * v4 * FXSCALE));
        atomicAdd(&acc[(r5.x & (NPB - 1)) * 64 + lane],
                  __float2int_rn(__int_as_float(r5.y) * v5 * FXSCALE));
        atomicAdd(&acc[(r6.x & (NPB - 1)) * 64 + lane],
                  __float2int_rn(__int_as_float(r6.y) * v6 * FXSCALE));
        atomicAdd(&acc[(r7.x & (NPB - 1)) * 64 + lane],
                  __float2int_rn(__int_as_float(r7.y) * v7 * FXSCALE));
    }
    for (; k < end; ++k) {
        int2 r0 = sb[k];
        float v0 = bf16f(x16[(r0.x >> 7) * D + lane]);
        atomicAdd(&acc[(r0.x & (NPB - 1)) * 64 + lane],
                  __float2int_rn(__int_as_float(r0.y) * v0 * FXSCALE));
    }
    __syncthreads();

    // epilogue: wave wv writes nodes wv*16 .. wv*16+15
    float W = weight[0];
    for (int dl = wv * 16; dl < wv * 16 + 16; ++dl) {
        int node = b * NPB + dl;
        if (node >= N_NODES) continue;
        float agg = (float)acc[dl * 64 + lane] * FXINV;
        float r = bf16f(x16[node * D + lane]) + W * agg;
        out[node * D + lane] = fmaxf(r, 0.f);
    }
}

// ---------------------------------------------------------------------------
// Fallback: atomic path (only if ws is tiny)
__global__ void init_out_kernel(const float4* __restrict__ x4,
                                float4* __restrict__ out4) {
    int i = blockIdx.x * blockDim.x + threadIdx.x;
    int stride = gridDim.x * blockDim.x;
    for (; i < OUT_N4; i += stride) out4[i] = x4[i];
}

__global__ __launch_bounds__(256) void scatter_atomic_kernel(
        const float* __restrict__ x,
        const void* __restrict__ ei_raw,
        const float* __restrict__ ew,
        const float* __restrict__ weight,
        const int* __restrict__ flag,
        float* __restrict__ out) {
    long long gid = (long long)blockIdx.x * blockDim.x + threadIdx.x;
    int e = (int)(gid >> 6);
    int d = (int)(gid & 63);
    if (e >= N_EDGES) return;
    int f = *flag;
    int src = load_idx(ei_raw, f, e);
    int dst = load_idx(ei_raw, f, (long long)N_EDGES + e);
    float w = weight[0] * ew[e];
    atomicAdd(&out[dst * D + d], w * x[src * D + d]);
}

__global__ void relu_kernel(float4* __restrict__ out4) {
    int i = blockIdx.x * blockDim.x + threadIdx.x;
    int stride = gridDim.x * blockDim.x;
    for (; i < OUT_N4; i += stride) {
        float4 v = out4[i];
        v.x = fmaxf(v.x, 0.0f);
        v.y = fmaxf(v.y, 0.0f);
        v.z = fmaxf(v.z, 0.0f);
        v.w = fmaxf(v.w, 0.0f);
        out4[i] = v;
    }
}

// ---------------------------------------------------------------------------
extern "C" void kernel_launch(void* const* d_in, const int* in_sizes, int n_in,
                              void* d_out, int out_size, void* d_ws, size_t ws_size,
                              hipStream_t stream) {
    const float* x      = (const float*)d_in[0];
    const void*  ei     = d_in[1];
    const float* ew     = (const float*)d_in[2];
    const float* weight = (const float*)d_in[3];
    float* out = (float*)d_out;

    char* w = (char*)d_ws;
    auto align256 = [](size_t v) { return (v + 255) & ~(size_t)255; };

    size_t off = 0;
    int* flag = (int*)(w + off);        off = align256(off + 4);
    int* cursor = (int*)(w + off);      off = align256(off + (size_t)NBUCK * CPAD * 4);
    unsigned short* x16 = (unsigned short*)(w + off);
                                        off = align256(off + (size_t)N_NODES * D * 2);
    int2* slots = (int2*)(w + off);     off = align256(off + (size_t)NBUCK * BCAP * 8);
    size_t needed = off;

    detect_kernel<<<1, 64, 0, stream>>>((const unsigned long long*)ei, flag);

    if (ws_size >= needed) {
        hipMemsetAsync(cursor, 0, (size_t)NBUCK * CPAD * 4, stream);
        part_kernel<<<PB, PTHREADS, 0, stream>>>((const float4*)x, (ushort4*)x16,
                                                 ei, ew, flag, cursor, slots);
        sg_kernel<<<NBUCK, SGT, 0, stream>>>(x16, cursor, slots, weight, out);
    } else {
        init_out_kernel<<<2048, 256, 0, stream>>>((const float4*)x, (float4*)out);
        long long total = (long long)N_EDGES * 64;
        scatter_atomic_kernel<<<(int)((total + 255) / 256), 256, 0, stream>>>(
            x, ei, ew, weight, flag, out);
        relu_kernel<<<2048, 256, 0, stream>>>((float4*)out);
    }
}

// Round 16
// 85.838 us; speedup vs baseline: 1.1704x; 1.1704x over previous
//
#include <hip/hip_runtime.h>

constexpr int N_NODES = 100000;
constexpr int D       = 64;
constexpr int N_EDGES = 1600000;
constexpr int OUT_N4  = N_NODES * D / 4;

constexpr int NPB   = 128;                           // nodes per bucket
constexpr int NBUCK = (N_NODES + NPB - 1) / NPB;     // 782
constexpr int BCAP  = 2560;                          // slots/bucket (λ=2046, +11σ)
constexpr int CPAD  = 32;                            // cursor pad (ints) = 128B/line
constexpr int PTHREADS = 1024;                       // part: 16 waves/block
constexpr int EPT   = 4;                             // part: edges per thread
constexpr int CHUNK = PTHREADS * EPT;                // 4096
constexpr int PB    = (N_EDGES + CHUNK - 1) / CHUNK; // 391

// ---------------------------------------------------------------------------
__global__ void detect_kernel(const unsigned long long* __restrict__ ei,
                              int* __restrict__ flag) {
    if (blockIdx.x == 0 && threadIdx.x == 0) {
        int is64 = 1;
#pragma unroll
        for (int i = 0; i < 8; ++i)
            if (ei[i] >= (unsigned long long)N_NODES) is64 = 0;
        *flag = is64;
    }
}

__device__ __forceinline__ int load_idx(const void* ei_raw, int flag, long long pos) {
    if (flag) return (int)((const long long*)ei_raw)[pos];
    return ((const int*)ei_raw)[pos];
}

__device__ __forceinline__ unsigned short bf16rne(float f) {
    unsigned u = __float_as_uint(f);
    unsigned r = (u + 0x7fffu + ((u >> 16) & 1u)) >> 16;
    return (unsigned short)r;
}

// ---------------------------------------------------------------------------
// Partition (+ fused bf16 conversion prologue): register-staged edges,
// in-LDS bucket sort, coalesced write-out. The streaming conversion overlaps
// the latency-bound partition phases (part is ~2% VALU-busy).
__global__ __launch_bounds__(PTHREADS) void part_kernel(
        const float4* __restrict__ x4,
        ushort4* __restrict__ x16v,
        const void* __restrict__ ei_raw,
        const float* __restrict__ ew,
        const int* __restrict__ flag,
        int* __restrict__ cursor,
        int2* __restrict__ slots) {
    __shared__ int  hist[NBUCK];
    __shared__ int  localbase[NBUCK];
    __shared__ int  runbase[NBUCK];
    __shared__ int  fill[NBUCK];
    __shared__ int  wsum[16];
    __shared__ int  tot;
    __shared__ int2 srt[CHUNK];           // 32 KB
    __shared__ unsigned short aux[CHUNK]; // 8 KB

    int tid  = threadIdx.x;
    int wv   = tid >> 6;
    int lane = tid & 63;
    for (int t = tid; t < NBUCK; t += PTHREADS) { hist[t] = 0; fill[t] = 0; }
    __syncthreads();

    // fused prologue: bf16 shadow of x (grid-stride over all part blocks)
    {
        int gstride = PB * PTHREADS;
        for (int i = blockIdx.x * PTHREADS + tid; i < OUT_N4; i += gstride) {
            float4 v = x4[i];
            ushort4 o;
            o.x = bf16rne(v.x); o.y = bf16rne(v.y);
            o.z = bf16rne(v.z); o.w = bf16rne(v.w);
            x16v[i] = o;
        }
    }

    int f = *flag;
    long long base = (long long)blockIdx.x * CHUNK;

    // Phase A: load edges once into registers; LDS histogram
    int  rb[EPT];
    int2 rrec[EPT];
#pragma unroll
    for (int it = 0; it < EPT; ++it) {
        long long e = base + it * PTHREADS + tid;
        if (e < N_EDGES) {
            int src = load_idx(ei_raw, f, e);
            int dst = load_idx(ei_raw, f, (long long)N_EDGES + e);
            int b = dst >> 7;
            rb[it] = b;
            rrec[it].x = (src << 7) | (dst & (NPB - 1));
            rrec[it].y = __float_as_int(ew[e]);
            atomicAdd(&hist[b], 1);
        } else {
            rb[it] = -1;
        }
    }
    __syncthreads();

    // Phase B: exclusive scan of hist[NBUCK] via shfl wave-scan
    int h = (tid < NBUCK) ? hist[tid] : 0;
    int v = h;
#pragma unroll
    for (int off = 1; off < 64; off <<= 1) {
        int u = __shfl_up(v, off, 64);
        if (lane >= off) v += u;
    }
    if (lane == 63) wsum[wv] = v;
    __syncthreads();
    if (wv == 0 && lane < 16) {
        int s = wsum[lane];
        int t2 = s;
#pragma unroll
        for (int off = 1; off < 16; off <<= 1) {
            int u = __shfl_up(t2, off, 64);
            if (lane >= off) t2 += u;
        }
        wsum[lane] = t2 - s;
        if (lane == 15) tot = t2;
    }
    __syncthreads();
    if (tid < NBUCK) {
        localbase[tid] = (v - h) + wsum[wv];
        int c = hist[tid];
        runbase[tid] = (c > 0) ? atomicAdd(&cursor[tid * CPAD], c) : 0;
    }
    __syncthreads();

    // Phase C: place records bucket-sorted into LDS
#pragma unroll
    for (int it = 0; it < EPT; ++it) {
        int b = rb[it];
        if (b >= 0) {
            int p = localbase[b] + atomicAdd(&fill[b], 1);
            srt[p] = rrec[it];
            aux[p] = (unsigned short)b;
        }
    }
    __syncthreads();

    // Phase D: linear write-out into per-bucket global runs
    int total = tot;
    for (int i = tid; i < total; i += PTHREADS) {
        int b = aux[i];
        int g = runbase[b] + (i - localbase[b]);
        if (g < BCAP) slots[(long long)b * BCAP + g] = srt[i];
    }
}

// ---------------------------------------------------------------------------
// Fused sort+gather (round-11/14 proven): one block (1024 thr, 16 waves) per
// bucket. Stage records in LDS, counting-sort by local node id (int LDS
// atomics only — NB: f32 LDS atomicAdd is a serializing CAS on gfx950,
// 13x slower; never use it), then each wave gathers 8 nodes:
// 8 lanes/record x ushort8 per lane (one wave-load = 8 random bf16 rows),
// shfl_xor butterfly, fused relu(x + w*agg) f32 write.
__global__ __launch_bounds__(PTHREADS) void sg_kernel(
        const unsigned short* __restrict__ x16,
        const int* __restrict__ cursor,
        const int2* __restrict__ slots,
        const float* __restrict__ weight,
        float* __restrict__ out) {
    __shared__ int  hist[NPB];
    __shared__ int  nbeg[NPB];
    __shared__ int  fill[NPB];
    __shared__ int2 raw[BCAP];   // 20 KB
    __shared__ int2 srt[BCAP];   // 20 KB

    int tid  = threadIdx.x;
    int wv   = tid >> 6;
    int lane = tid & 63;
    int b    = blockIdx.x;

    if (tid < NPB) { hist[tid] = 0; fill[tid] = 0; }
    __syncthreads();

    int cnt = cursor[b * CPAD];
    if (cnt > BCAP) cnt = BCAP;
    const int2* sb = slots + (long long)b * BCAP;

    // stage + per-node histogram
    for (int i = tid; i < cnt; i += PTHREADS) {
        int2 r = sb[i];
        raw[i] = r;
        atomicAdd(&hist[r.x & (NPB - 1)], 1);
    }
    __syncthreads();

    // wave 0: exclusive scan of hist[128] (2 elems/lane, shfl scan)
    if (wv == 0) {
        int h0 = hist[2 * lane];
        int h1 = hist[2 * lane + 1];
        int s  = h0 + h1;
        int v  = s;
#pragma unroll
        for (int off = 1; off < 64; off <<= 1) {
            int u = __shfl_up(v, off, 64);
            if (lane >= off) v += u;
        }
        int excl = v - s;
        nbeg[2 * lane]     = excl;
        nbeg[2 * lane + 1] = excl + h0;
    }
    __syncthreads();

    // counting-sort placement into srt
    for (int i = tid; i < cnt; i += PTHREADS) {
        int2 r = raw[i];
        int dl = r.x & (NPB - 1);
        int pos = nbeg[dl] + atomicAdd(&fill[dl], 1);
        srt[pos] = r;
    }
    __syncthreads();

    // gather: wave wv handles local nodes wv*8 .. wv*8+7
    int rg = lane >> 3;   // record group 0..7
    int dg = lane & 7;    // dim group: dims dg*8 .. dg*8+7
    float W = weight[0];

    for (int dl = wv * 8; dl < wv * 8 + 8; ++dl) {
        int node = b * NPB + dl;
        if (node >= N_NODES) continue;
        int nb = nbeg[dl];
        int nc = hist[dl];

        float acc[8];
#pragma unroll
        for (int j = 0; j < 8; ++j) acc[j] = 0.f;

        for (int k = 0; k < nc; k += 16) {
            int iA = k + rg;
            int iB = iA + 8;
            int2 rA = srt[nb + (iA < nc ? iA : 0)];
            int2 rB = srt[nb + (iB < nc ? iB : 0)];
            float wA = (iA < nc) ? __int_as_float(rA.y) : 0.f;
            float wB = (iB < nc) ? __int_as_float(rB.y) : 0.f;
            uint4 xa = *(const uint4*)(x16 + (rA.x >> 7) * D + dg * 8);
            uint4 xb = *(const uint4*)(x16 + (rB.x >> 7) * D + dg * 8);
#pragma unroll
            for (int j = 0; j < 4; ++j) {
                unsigned ua = ((const unsigned*)&xa)[j];
                acc[2 * j]     += wA * __uint_as_float(ua << 16);
                acc[2 * j + 1] += wA * __uint_as_float(ua & 0xffff0000u);
            }
#pragma unroll
            for (int j = 0; j < 4; ++j) {
                unsigned ub = ((const unsigned*)&xb)[j];
                acc[2 * j]     += wB * __uint_as_float(ub << 16);
                acc[2 * j + 1] += wB * __uint_as_float(ub & 0xffff0000u);
            }
        }

        // fold 8 record groups (lane bits 3,4,5)
#pragma unroll
        for (int j = 0; j < 8; ++j) {
            acc[j] += __shfl_xor(acc[j], 8, 64);
            acc[j] += __shfl_xor(acc[j], 16, 64);
            acc[j] += __shfl_xor(acc[j], 32, 64);
        }

        if (rg == 0) {
            uint4 xs = *(const uint4*)(x16 + node * D + dg * 8);
            float o[8];
#pragma unroll
            for (int j = 0; j < 4; ++j) {
                unsigned us = ((const unsigned*)&xs)[j];
                o[2 * j]     = fmaxf(__uint_as_float(us << 16)         + W * acc[2 * j],     0.f);
                o[2 * j + 1] = fmaxf(__uint_as_float(us & 0xffff0000u) + W * acc[2 * j + 1], 0.f);
            }
            float4* po = (float4*)(out + node * D + dg * 8);
            po[0] = make_float4(o[0], o[1], o[2], o[3]);
            po[1] = make_float4(o[4], o[5], o[6], o[7]);
        }
    }
}

// ---------------------------------------------------------------------------
// Fallback: atomic path (only if ws is tiny)
__global__ void init_out_kernel(const float4* __restrict__ x4,
                                float4* __restrict__ out4) {
    int i = blockIdx.x * blockDim.x + threadIdx.x;
    int stride = gridDim.x * blockDim.x;
    for (; i < OUT_N4; i += stride) out4[i] = x4[i];
}

__global__ __launch_bounds__(256) void scatter_atomic_kernel(
        const float* __restrict__ x,
        const void* __restrict__ ei_raw,
        const float* __restrict__ ew,
        const float* __restrict__ weight,
        const int* __restrict__ flag,
        float* __restrict__ out) {
    long long gid = (long long)blockIdx.x * blockDim.x + threadIdx.x;
    int e = (int)(gid >> 6);
    int d = (int)(gid & 63);
    if (e >= N_EDGES) return;
    int f = *flag;
    int src = load_idx(ei_raw, f, e);
    int dst = load_idx(ei_raw, f, (long long)N_EDGES + e);
    float w = weight[0] * ew[e];
    atomicAdd(&out[dst * D + d], w * x[src * D + d]);
}

__global__ void relu_kernel(float4* __restrict__ out4) {
    int i = blockIdx.x * blockDim.x + threadIdx.x;
    int stride = gridDim.x * blockDim.x;
    for (; i < OUT_N4; i += stride) {
        float4 v = out4[i];
        v.x = fmaxf(v.x, 0.0f);
        v.y = fmaxf(v.y, 0.0f);
        v.z = fmaxf(v.z, 0.0f);
        v.w = fmaxf(v.w, 0.0f);
        out4[i] = v;
    }
}

// ---------------------------------------------------------------------------
extern "C" void kernel_launch(void* const* d_in, const int* in_sizes, int n_in,
                              void* d_out, int out_size, void* d_ws, size_t ws_size,
                              hipStream_t stream) {
    const float* x      = (const float*)d_in[0];
    const void*  ei     = d_in[1];
    const float* ew     = (const float*)d_in[2];
    const float* weight = (const float*)d_in[3];
    float* out = (float*)d_out;

    char* w = (char*)d_ws;
    auto align256 = [](size_t v) { return (v + 255) & ~(size_t)255; };

    size_t off = 0;
    int* flag = (int*)(w + off);        off = align256(off + 4);
    int* cursor = (int*)(w + off);      off = align256(off + (size_t)NBUCK * CPAD * 4);
    unsigned short* x16 = (unsigned short*)(w + off);
                                        off = align256(off + (size_t)N_NODES * D * 2);
    int2* slots = (int2*)(w + off);     off = align256(off + (size_t)NBUCK * BCAP * 8);
    size_t needed = off;

    detect_kernel<<<1, 64, 0, stream>>>((const unsigned long long*)ei, flag);

    if (ws_size >= needed) {
        hipMemsetAsync(cursor, 0, (size_t)NBUCK * CPAD * 4, stream);
        part_kernel<<<PB, PTHREADS, 0, stream>>>((const float4*)x, (ushort4*)x16,
                                                 ei, ew, flag, cursor, slots);
        sg_kernel<<<NBUCK, PTHREADS, 0, stream>>>(x16, cursor, slots, weight, out);
    } else {
        init_out_kernel<<<2048, 256, 0, stream>>>((const float4*)x, (float4*)out);
        long long total = (long long)N_EDGES * 64;
        scatter_atomic_kernel<<<(int)((total + 255) / 256), 256, 0, stream>>>(
            x, ei, ew, weight, flag, out);
        relu_kernel<<<2048, 256, 0, stream>>>((float4*)out);
    }
}